// Round 9
// baseline (6479.680 us; speedup 1.0000x reference)
//
#include <hip/hip_runtime.h>

// Persistent 2-layer LSTM, plain launch (grid=256=#CUs, 1 block/CU).
// 8 row-groups x 32 col-WGs; WG = 32 batch rows x 64 gate cols (16 units).
// Split-fp16 B (hi+lo in registers), A = fp16 hi only. Staging via bulk async
// global_load_lds (aux sc0|sc1 -> LLC-coherent), split h1/h2 for overlap.
// h-state written as 16-B packed volatile stores (LDS repack). Per-group
// flags packed into ONE 128-B line. One barrier per tick.

#define WGS    256
#define NTHR   256
#define TSTEPS 512
#define HDIM   512
#define BATCH  256
#define FUT    8
#define NCOL   (TSTEPS + FUT)
#define HPLANE (BATCH * HDIM)   // one h plane (fp16 hi only)
#define ROWB   1032             // LDS row pitch bytes (1024 + 8 pad)
#define GPITCH 68               // g-tile row pitch (floats)

typedef _Float16 half_t;
typedef _Float16 f16x8 __attribute__((ext_vector_type(8)));
typedef float    f32x4 __attribute__((ext_vector_type(4)));
typedef __attribute__((address_space(1))) const unsigned int gu32;
typedef __attribute__((address_space(3))) unsigned int su32;

struct Params {
  const float* input_t;
  const float* W_ih1; const float* b_ih1; const float* W_hh1; const float* b_hh1;
  const float* W_ih2; const float* b_ih2; const float* W_hh2; const float* b_hh2;
  const float* W_lin; const float* b_lin;
  float* out;
  unsigned* flags;     // [8 groups][32 u32] -- one 128-B line per group
  float* outfeed;
  half_t* h1buf;   // [2 pp][BATCH][HDIM]
  half_t* h2buf;   // [2 pp][BATCH][HDIM]
};

__device__ __forceinline__ float sigm(float x)   { return 1.0f / (1.0f + expf(-x)); }
__device__ __forceinline__ float tanh_f(float x) { return tanhf(x); }

// LLC-coherent (sc0 sc1) 16-B load — volatile => bypasses stale L1/L2.
__device__ __forceinline__ f16x8 vload8(const half_t* p) {
  return *(const volatile f16x8*)p;
}

// fp32 row -> (hi, lo) fp16 fragments
__device__ __forceinline__ void load8_split(const float* p, f16x8& hi, f16x8& lo) {
  const float4 a = *(const float4*)p;
  const float4 b = *(const float4*)(p + 4);
  float v[8] = {a.x, a.y, a.z, a.w, b.x, b.y, b.z, b.w};
#pragma unroll
  for (int i = 0; i < 8; ++i) {
    const half_t h = (half_t)v[i];
    hi[i] = h;
    lo[i] = (half_t)(v[i] - (float)h);
  }
}

// Group barrier (32 WGs sharing a row-group). Flags for the whole group live
// in ONE 128-B line: store own u32 (parallel), lanes 0..31 poll the line with
// one coalesced request per iteration.
__device__ __forceinline__ void groupbar(unsigned* flags, int grp, int cgi, unsigned target) {
  __syncthreads();   // s_waitcnt vmcnt(0) + s_barrier: packed h stores at LLC
  if (threadIdx.x == 0) {
    __hip_atomic_store(&flags[grp * 32 + cgi], target,
                       __ATOMIC_RELAXED, __HIP_MEMORY_SCOPE_AGENT);
  }
  if (threadIdx.x < 32) {
    unsigned iters = 0;
    while (__hip_atomic_load(&flags[grp * 32 + threadIdx.x],
                             __ATOMIC_RELAXED, __HIP_MEMORY_SCOPE_AGENT) < target) {
      __builtin_amdgcn_s_sleep(1);
      if (++iters > 5000000u) break;  // failsafe, prevents suite hang
    }
  }
  __syncthreads();
}

__global__ void __launch_bounds__(NTHR, 1) lstm_fused(Params P) {
  const int tid  = threadIdx.x;
  const int wg   = blockIdx.x;
  const int cg   = wg & 31;    // col group: hidden units cg*16 .. +15
  const int rb   = wg >> 5;    // row group: batch rows rb*32 .. +31
  const int wv   = tid >> 6;   // wave 0..3 == gate index (i,f,g,o)
  const int lane = tid & 63;
  const int m    = lane & 15;
  const int quad = lane >> 4;

  __shared__ __align__(16) char ldsA1[32 * ROWB];  // staged h1 rows (33 KB)
  __shared__ __align__(16) char ldsA2[32 * ROWB];  // staged h2 rows (33 KB)
  __shared__ float g1s[32 * GPITCH];               // L1 gate pre-acts [row][p]
  __shared__ float g2s[32 * GPITCH];               // L2 gate pre-acts
  __shared__ __align__(16) half_t h1pk[32 * 16];   // packed h1 tile (1 KB)
  __shared__ __align__(16) half_t h2pk[32 * 16];   // packed h2 tile (1 KB)
  __shared__ float in_s[32];
  __shared__ float bias1_s[64];
  __shared__ float w1x_s[64];
  __shared__ float bias2_s[64];

  if (tid < 64) {   // p = tid: gate = p>>4, ul = p&15
    const int gate = tid >> 4, ul = tid & 15;
    const int gc = gate * HDIM + cg * 16 + ul;
    bias1_s[tid] = P.b_ih1[gc] + P.b_hh1[gc];
    w1x_s[tid]   = P.W_ih1[gc];
    bias2_s[tid] = P.b_ih2[gc] + P.b_hh2[gc];
  }
  if (tid < 32) in_s[tid] = P.input_t[rb * 32 + tid];

  // Register-resident fp16 B fragments (hi+lo, all three matrices).
  // mfma_f32_16x16x32_f16 B layout: lane L holds B[k=(L>>4)*8+j][n=L&15].
  f16x8 B1h[16], B1l[16];   // W_hh1
  f16x8 B2h[32], B2l[32];   // [0..15]=W_ih2, [16..31]=W_hh2
  {
    const int gc = wv * HDIM + cg * 16 + m;   // this lane's B column
    const float* w1r  = P.W_hh1 + (size_t)gc * HDIM;
    const float* wi2r = P.W_ih2 + (size_t)gc * HDIM;
    const float* wh2r = P.W_hh2 + (size_t)gc * HDIM;
#pragma unroll
    for (int kk = 0; kk < 16; ++kk) {
      const int k0 = kk * 32 + quad * 8;
      load8_split(w1r + k0, B1h[kk], B1l[kk]);
      load8_split(wi2r + k0, B2h[kk], B2l[kk]);
      load8_split(wh2r + k0, B2h[16 + kk], B2l[16 + kk]);
    }
  }
  __syncthreads();

  float c1[2] = {0.f, 0.f}, c2[2] = {0.f, 0.f};   // cell state (fp32, registers)
  const int eb  = tid >> 3;        // elementwise: batch row 0..31
  const int eu0 = (tid & 7) * 2;   // elementwise: first of 2 units (0..14)

  // Bulk async stage of one 32-row h plane: 8 rows per wave.
  auto stage = [&](const half_t* hp, char* ldst) {
#pragma unroll
    for (int r = 0; r < 8; ++r) {
      const int row = wv * 8 + r;
      const half_t* g = hp + (size_t)(rb * 32 + row) * HDIM + lane * 8;
      __builtin_amdgcn_global_load_lds((gu32*)g, (su32*)(ldst + row * ROWB), 16, 0, 0x11);
    }
  };

  // Output row: WG wg handles batch row wg (row wg is inside its own group).
  auto outrow = [&](const half_t* h2p, int col) {
    if (tid < 64) {
      const f16x8 hv = vload8(h2p + (size_t)wg * HDIM + lane * 8);
      const float4 wa = *(const float4*)(P.W_lin + lane * 8);
      const float4 wb = *(const float4*)(P.W_lin + lane * 8 + 4);
      float s = (float)hv[0]*wa.x + (float)hv[1]*wa.y + (float)hv[2]*wa.z + (float)hv[3]*wa.w
              + (float)hv[4]*wb.x + (float)hv[5]*wb.y + (float)hv[6]*wb.z + (float)hv[7]*wb.w;
#pragma unroll
      for (int off = 32; off > 0; off >>= 1) s += __shfl_down(s, off);
      if (lane == 0) {
        s += P.b_lin[0];
        P.out[(size_t)wg * NCOL + col] = s;
        *(volatile float*)&P.outfeed[wg] = s;
      }
    }
  };

  auto tick = [&](bool doL1, bool doL2, bool doOUT, bool future, int outcol,
                  const half_t* h1rp, half_t* h1wp,
                  const half_t* h2rp, half_t* h2wp) {
    if (doL1 | doL2) stage(h1rp, ldsA1);   // phase-A operand
    if (doOUT) outrow(h2rp, outcol);       // overlaps with staging in flight

    const f32x4 z4 = {0.f, 0.f, 0.f, 0.f};
    f32x4 acc1[2] = {z4, z4};
    f32x4 acc2[2] = {z4, z4};

    __syncthreads();              // h1 (and outrow) drained; ldsA1 ready
    if (doL2) stage(h2rp, ldsA2); // phase-B operand arrives during phase A

    // A layout: lane L holds A[m=L&15][k=(L>>4)*8+j]; row tile rt: rows rt*16+m.
    const char* a1p = ldsA1 + m * ROWB + quad * 16;
    const char* a2p = ldsA2 + m * ROWB + quad * 16;

    if (doL1 | doL2) {
#pragma unroll
      for (int kk = 0; kk < 16; ++kk) {   // Phase A: A = h1[t-1]
        const int o = kk * 64;
        const f16x8 a0 = *(const f16x8*)(a1p + o);
        const f16x8 a1 = *(const f16x8*)(a1p + 16 * ROWB + o);
        if (doL1) {
          acc1[0] = __builtin_amdgcn_mfma_f32_16x16x32_f16(a0, B1h[kk], acc1[0], 0, 0, 0);
          acc1[1] = __builtin_amdgcn_mfma_f32_16x16x32_f16(a1, B1h[kk], acc1[1], 0, 0, 0);
          acc1[0] = __builtin_amdgcn_mfma_f32_16x16x32_f16(a0, B1l[kk], acc1[0], 0, 0, 0);
          acc1[1] = __builtin_amdgcn_mfma_f32_16x16x32_f16(a1, B1l[kk], acc1[1], 0, 0, 0);
        }
        if (doL2) {
          acc2[0] = __builtin_amdgcn_mfma_f32_16x16x32_f16(a0, B2h[kk], acc2[0], 0, 0, 0);
          acc2[1] = __builtin_amdgcn_mfma_f32_16x16x32_f16(a1, B2h[kk], acc2[1], 0, 0, 0);
          acc2[0] = __builtin_amdgcn_mfma_f32_16x16x32_f16(a0, B2l[kk], acc2[0], 0, 0, 0);
          acc2[1] = __builtin_amdgcn_mfma_f32_16x16x32_f16(a1, B2l[kk], acc2[1], 0, 0, 0);
        }
      }
    }
    if (doL2) {
      __syncthreads();   // ldsA2 staged (phase A covered most of the latency)
#pragma unroll
      for (int kk = 0; kk < 16; ++kk) {   // Phase B: A = h2[t-2]
        const int o = kk * 64;
        const f16x8 a0 = *(const f16x8*)(a2p + o);
        const f16x8 a1 = *(const f16x8*)(a2p + 16 * ROWB + o);
        acc2[0] = __builtin_amdgcn_mfma_f32_16x16x32_f16(a0, B2h[16 + kk], acc2[0], 0, 0, 0);
        acc2[1] = __builtin_amdgcn_mfma_f32_16x16x32_f16(a1, B2h[16 + kk], acc2[1], 0, 0, 0);
        acc2[0] = __builtin_amdgcn_mfma_f32_16x16x32_f16(a0, B2l[16 + kk], acc2[0], 0, 0, 0);
        acc2[1] = __builtin_amdgcn_mfma_f32_16x16x32_f16(a1, B2l[16 + kk], acc2[1], 0, 0, 0);
      }
    }

    // C/D layout: col = lane&15 (tile col), row = rt*16 + quad*4 + reg.
    if (doL1) {
#pragma unroll
      for (int rt = 0; rt < 2; ++rt)
#pragma unroll
        for (int rg = 0; rg < 4; ++rg)
          g1s[(rt * 16 + quad * 4 + rg) * GPITCH + wv * 16 + m] = acc1[rt][rg];
    }
    if (doL2) {
#pragma unroll
      for (int rt = 0; rt < 2; ++rt)
#pragma unroll
        for (int rg = 0; rg < 4; ++rg)
          g2s[(rt * 16 + quad * 4 + rg) * GPITCH + wv * 16 + m] = acc2[rt][rg];
    }
    __syncthreads();

    // Elementwise: thread owns 2 (b,u) pairs; c-state stays in registers.
    // h goes to a packed LDS tile, then 16-B volatile global stores.
    float xb = 0.f;
    if (doL1) xb = future ? *(volatile const float*)&P.outfeed[rb * 32 + eb] : in_s[eb];
    if (doL1) {
#pragma unroll
      for (int uu = 0; uu < 2; ++uu) {
        const int u = eu0 + uu;
        const float ai = g1s[eb * GPITCH + u]      + xb * w1x_s[u]      + bias1_s[u];
        const float af = g1s[eb * GPITCH + 16 + u] + xb * w1x_s[16 + u] + bias1_s[16 + u];
        const float ag = g1s[eb * GPITCH + 32 + u] + xb * w1x_s[32 + u] + bias1_s[32 + u];
        const float ao = g1s[eb * GPITCH + 48 + u] + xb * w1x_s[48 + u] + bias1_s[48 + u];
        const float ig = sigm(ai), fg = sigm(af), gg = tanh_f(ag), og = sigm(ao);
        const float c = fg * c1[uu] + ig * gg;
        c1[uu] = c;
        h1pk[eb * 16 + u] = (half_t)(og * tanh_f(c));
      }
    }
    if (doL2) {
#pragma unroll
      for (int uu = 0; uu < 2; ++uu) {
        const int u = eu0 + uu;
        const float ai = g2s[eb * GPITCH + u]      + bias2_s[u];
        const float af = g2s[eb * GPITCH + 16 + u] + bias2_s[16 + u];
        const float ag = g2s[eb * GPITCH + 32 + u] + bias2_s[32 + u];
        const float ao = g2s[eb * GPITCH + 48 + u] + bias2_s[48 + u];
        const float ig = sigm(ai), fg = sigm(af), gg = tanh_f(ag), og = sigm(ao);
        const float c = fg * c2[uu] + ig * gg;
        c2[uu] = c;
        h2pk[eb * 16 + u] = (half_t)(og * tanh_f(c));
      }
    }
    __syncthreads();   // packed tiles complete

    // 16-B packed volatile stores: wave 0 -> h1 (64 stores), wave 1 -> h2.
    if (doL1 && tid < 64) {
      const int row = tid >> 1, chunk = tid & 1;
      const f16x8 v = *(const f16x8*)&h1pk[row * 16 + chunk * 8];
      *(volatile f16x8*)(h1wp + (size_t)(rb * 32 + row) * HDIM + cg * 16 + chunk * 8) = v;
    }
    if (doL2 && tid >= 64 && tid < 128) {
      const int t2 = tid - 64;
      const int row = t2 >> 1, chunk = t2 & 1;
      const f16x8 v = *(const f16x8*)&h2pk[row * 16 + chunk * 8];
      *(volatile f16x8*)(h2wp + (size_t)(rb * 32 + row) * HDIM + cg * 16 + chunk * 8) = v;
    }
  };

  half_t* h1b0 = P.h1buf;  half_t* h1b1 = P.h1buf + HPLANE;
  half_t* h2b0 = P.h2buf;  half_t* h2b1 = P.h2buf + HPLANE;

  unsigned bid = 0;
  // Main pipelined ticks: tick t = L1 step t, L2 step t-1, OUT step t-2.
  for (int t = 0; t <= TSTEPS; ++t) {
    half_t* h1r = ((t + 1) & 1) ? h1b1 : h1b0;   // h1[t-1]
    half_t* h1w = (t & 1)       ? h1b1 : h1b0;   // h1[t]
    half_t* h2r = (t & 1)       ? h2b1 : h2b0;   // h2[t-2]
    half_t* h2w = ((t + 1) & 1) ? h2b1 : h2b0;   // h2[t-1]
    tick(t < TSTEPS, t >= 1, t >= 2, false, t - 2, h1r, h1w, h2r, h2w);
    groupbar(P.flags, rb, cg, ++bid);
  }
  // Autoregressive future steps: out feeds back => 3 phases each.
  for (int k = 0; k < FUT; ++k) {
    const int s = TSTEPS + k;
    const half_t* h2last = (((s - 1) & 1)) ? h2b1 : h2b0;  // h2[s-1]
    outrow(h2last, s - 1);
    groupbar(P.flags, rb, cg, ++bid);
    {  // L1 future step s (x = outfeed)
      half_t* h1r = (((s - 1) & 1)) ? h1b1 : h1b0;
      half_t* h1w = ((s & 1))       ? h1b1 : h1b0;
      tick(true, false, false, true, 0, h1r, h1w, h2b0, h2b0);
      groupbar(P.flags, rb, cg, ++bid);
    }
    {  // L2 future step s (x = h1[s], hidden = h2[s-1])
      half_t* h1r = ((s & 1))       ? h1b1 : h1b0;
      half_t* h2r = (((s - 1) & 1)) ? h2b1 : h2b0;
      half_t* h2w = ((s & 1))       ? h2b1 : h2b0;
      tick(false, true, false, false, 0, h1r, h1b0, h2r, h2w);
      groupbar(P.flags, rb, cg, ++bid);
    }
  }
  outrow((((TSTEPS + 7) & 1)) ? h2b1 : h2b0, TSTEPS + 7);
}

extern "C" void kernel_launch(void* const* d_in, const int* in_sizes, int n_in,
                              void* d_out, int out_size, void* d_ws, size_t ws_size,
                              hipStream_t stream) {
  Params P;
  P.input_t = (const float*)d_in[0];
  // d_in[1] = y : only its shape (T) matters; T hardcoded 512
  P.W_ih1 = (const float*)d_in[2];  P.b_ih1 = (const float*)d_in[3];
  P.W_hh1 = (const float*)d_in[4];  P.b_hh1 = (const float*)d_in[5];
  P.W_ih2 = (const float*)d_in[6];  P.b_ih2 = (const float*)d_in[7];
  P.W_hh2 = (const float*)d_in[8];  P.b_hh2 = (const float*)d_in[9];
  P.W_lin = (const float*)d_in[10]; P.b_lin = (const float*)d_in[11];
  P.out   = (float*)d_out;

  char* ws = (char*)d_ws;
  P.outfeed = (float*)(ws + 256);
  P.flags   = (unsigned*)(ws + 2048);                                 // 8*128 B = 1 KB
  P.h1buf   = (half_t*)(ws + 4096);                                   // [2][B][H] = 512 KB
  P.h2buf   = (half_t*)(ws + 4096 + 2 * (size_t)HPLANE * sizeof(half_t));
  const size_t need = 4096 + 4 * (size_t)HPLANE * sizeof(half_t);     // ~1.05 MB

  (void)hipMemsetAsync(d_ws, 0, need, stream);  // zero flags + outfeed + h buffers

  // PLAIN launch: grid == 256 CUs, 1 block/CU by resources => all resident.
  lstm_fused<<<dim3(WGS), dim3(NTHR), 0, stream>>>(P);
}